// Round 1
// baseline (1449.736 us; speedup 1.0000x reference)
//
#include <hip/hip_runtime.h>

#define N_NODES 50000
#define N_EDGES 800000
#define FEAT 128
#define HID 256
#define N_GRAPHS 64

// ---------------- graph preprocessing ----------------

__global__ void hist_kernel(const int* __restrict__ dst, int* __restrict__ cnt, int e) {
  int i = blockIdx.x * blockDim.x + threadIdx.x;
  if (i < e) atomicAdd(&cnt[dst[i]], 1);
}

__global__ void dinv_kernel(const int* __restrict__ cnt, float* __restrict__ dinv, int n) {
  int i = blockIdx.x * blockDim.x + threadIdx.x;
  if (i < n) dinv[i] = 1.0f / sqrtf((float)cnt[i] + 1.0f);
}

__global__ void scan_kernel(const int* __restrict__ cnt, int* __restrict__ rowptr, int n) {
  __shared__ int part[1024];
  int tid = threadIdx.x;
  int per = (n + 1023) >> 10;
  int beg = min(tid * per, n), end = min(beg + per, n);
  int s = 0;
  for (int i = beg; i < end; ++i) s += cnt[i];
  part[tid] = s;
  __syncthreads();
  for (int off = 1; off < 1024; off <<= 1) {
    int v = (tid >= off) ? part[tid - off] : 0;
    __syncthreads();
    part[tid] += v;
    __syncthreads();
  }
  int run = (tid == 0) ? 0 : part[tid - 1];
  for (int i = beg; i < end; ++i) { rowptr[i] = run; run += cnt[i]; }
  if (tid == 1023) rowptr[n] = run;
}

__global__ void place_kernel(const int* __restrict__ dst, const int* __restrict__ rowptr,
                             int* __restrict__ cursor, int* __restrict__ csr, int e) {
  int i = blockIdx.x * blockDim.x + threadIdx.x;
  if (i < e) {
    int d = dst[i];
    int slot = rowptr[d] + atomicAdd(&cursor[d], 1);
    csr[slot] = i;  // store edge id for deterministic per-row sort
  }
}

// sort each row's edge ids ascending (determinism), then rewrite as (src, dinv[src])
__global__ void sortrow_kernel(int* __restrict__ csr, float* __restrict__ csr_w,
                               const int* __restrict__ rowptr, const int* __restrict__ src,
                               const float* __restrict__ dinv, int n) {
  int d = blockIdx.x * blockDim.x + threadIdx.x;
  if (d >= n) return;
  int beg = rowptr[d], len = rowptr[d + 1] - beg;
  if (len <= 64) {
    int buf[64];
    for (int j = 0; j < len; ++j) buf[j] = csr[beg + j];
    for (int j = 1; j < len; ++j) {
      int v = buf[j]; int k = j - 1;
      while (k >= 0 && buf[k] > v) { buf[k + 1] = buf[k]; --k; }
      buf[k + 1] = v;
    }
    for (int j = 0; j < len; ++j) {
      int s = src[buf[j]];
      csr[beg + j] = s; csr_w[beg + j] = dinv[s];
    }
  } else {  // statistically impossible (Poisson(16)), keep correct anyway
    for (int j = 0; j < len; ++j) {
      int s = src[csr[beg + j]];
      csr[beg + j] = s; csr_w[beg + j] = dinv[s];
    }
  }
}

__global__ void bounds_kernel(const int* __restrict__ batch, int* __restrict__ bounds,
                              int n, int g) {
  int t = threadIdx.x;
  if (t > g) return;
  int lo = 0, hi = n;
  while (lo < hi) { int mid = (lo + hi) >> 1; if (batch[mid] < t) lo = mid + 1; else hi = mid; }
  bounds[t] = lo;
}

// ---------------- aggregation: out[d] = dinv[d]*sum_j dinv[s_j]*T[s_j] + T[d]*dinv[d]^2 (+b, relu)
template <int F, bool BIAS, bool RELU>
__global__ void agg_kernel(const float* __restrict__ T, const int* __restrict__ rowptr,
                           const int* __restrict__ csr, const float* __restrict__ csr_w,
                           const float* __restrict__ dinv, const float* __restrict__ bias,
                           float* __restrict__ out) {
  int d = blockIdx.x;
  int f = threadIdx.x;
  int beg = rowptr[d], end = rowptr[d + 1];
  float acc = 0.f;
  for (int j = beg; j < end; ++j) {
    int s = csr[j];
    float w = csr_w[j];
    acc += w * T[(size_t)s * F + f];
  }
  float di = dinv[d];
  float v = acc * di + T[(size_t)d * F + f] * di * di;
  if (BIAS) v += bias[f];
  if (RELU) v = fmaxf(v, 0.f);
  out[(size_t)d * F + f] = v;
}

// ---------------- f32 GEMM: C[N x 256] = A[N x K] @ B[K x 256] (+bias)(+gi2[batch])(relu)
#define BM 64
#define BK 32
template <int K, bool BIAS, bool RELU, bool GIADD>
__global__ __launch_bounds__(256) void gemm_kernel(
    const float* __restrict__ A, const float* __restrict__ B,
    const float* __restrict__ bias, const float* __restrict__ gi2,
    const int* __restrict__ batch, float* __restrict__ C, int nrows) {
  __shared__ float Xs[BM][BK + 1];   // padded: conflict-free staging writes
  __shared__ float Ws[BK][HID];
  int tid = threadIdx.x;
  int rg = tid >> 6;        // wave id 0..3 -> row group
  int cg = tid & 63;        // lane -> col group
  int c0 = cg * 4;
  int row0 = blockIdx.x * BM;
  float acc[16][4];
  #pragma unroll
  for (int r = 0; r < 16; ++r)
    { acc[r][0] = 0.f; acc[r][1] = 0.f; acc[r][2] = 0.f; acc[r][3] = 0.f; }

  for (int kc = 0; kc < K; kc += BK) {
    #pragma unroll
    for (int i = 0; i < 8; ++i) {   // stage A tile 64x32
      int e = i * 256 + tid;
      int r = e >> 5, k = e & 31;
      int row = row0 + r;
      Xs[r][k] = (row < nrows) ? A[(size_t)row * K + kc + k] : 0.f;
    }
    #pragma unroll
    for (int i = 0; i < 32; ++i) {  // stage B tile 32x256
      int e = i * 256 + tid;
      int k = e >> 8, c = e & 255;
      Ws[k][c] = B[(size_t)(kc + k) * HID + c];
    }
    __syncthreads();
    #pragma unroll 4
    for (int k = 0; k < BK; ++k) {
      float4 wv = *(const float4*)&Ws[k][c0];
      #pragma unroll
      for (int rr = 0; rr < 16; ++rr) {
        float x = Xs[rg * 16 + rr][k];   // broadcast within wave
        acc[rr][0] += x * wv.x; acc[rr][1] += x * wv.y;
        acc[rr][2] += x * wv.z; acc[rr][3] += x * wv.w;
      }
    }
    __syncthreads();
  }
  float4 bv = make_float4(0.f, 0.f, 0.f, 0.f);
  if (BIAS) bv = *(const float4*)&bias[c0];
  #pragma unroll
  for (int rr = 0; rr < 16; ++rr) {
    int row = row0 + rg * 16 + rr;
    if (row < nrows) {
      float vx = acc[rr][0] + bv.x, vy = acc[rr][1] + bv.y;
      float vz = acc[rr][2] + bv.z, vw = acc[rr][3] + bv.w;
      if (GIADD) {
        const float4 g = *(const float4*)&gi2[(size_t)batch[row] * HID + c0];
        vx += g.x; vy += g.y; vz += g.z; vw += g.w;
      }
      if (RELU) { vx = fmaxf(vx, 0.f); vy = fmaxf(vy, 0.f);
                  vz = fmaxf(vz, 0.f); vw = fmaxf(vw, 0.f); }
      *(float4*)&C[(size_t)row * HID + c0] = make_float4(vx, vy, vz, vw);
    }
  }
}

// ---------------- fused pooling -> fc1 -> @W2[256:512] : gi2[64 x 256]
__global__ void poolfc_kernel(const float* __restrict__ h0, const int* __restrict__ bounds,
                              const float* __restrict__ Wf, const float* __restrict__ bf,
                              const float* __restrict__ W2, float* __restrict__ gi2) {
  int g = blockIdx.x;
  int c = threadIdx.x;  // 256 threads
  __shared__ float P[HID];
  __shared__ float GI[HID];
  int beg = bounds[g], end = bounds[g + 1];
  float m = -INFINITY;
  for (int i = beg; i < end; ++i) m = fmaxf(m, h0[(size_t)i * HID + c]);
  P[c] = m;
  __syncthreads();
  float acc = 0.f;
  for (int k = 0; k < HID; ++k) acc += P[k] * Wf[k * HID + c];
  GI[c] = acc + bf[c];
  __syncthreads();
  float acc2 = 0.f;
  for (int k = 0; k < HID; ++k) acc2 += GI[k] * W2[(HID + k) * HID + c];
  gi2[g * HID + c] = acc2;
}

// ---------------- last layer: t3 = h2 @ W3  (one wave per node)
__global__ void dot_kernel(const float* __restrict__ H, const float* __restrict__ W3,
                           float* __restrict__ t3, int n) {
  int gt = blockIdx.x * blockDim.x + threadIdx.x;
  int wid = gt >> 6;
  int lane = gt & 63;
  if (wid >= n) return;
  float4 h = *(const float4*)&H[(size_t)wid * HID + lane * 4];
  float4 w = *(const float4*)&W3[lane * 4];
  float s = h.x * w.x + h.y * w.y + h.z * w.z + h.w * w.w;
  for (int off = 32; off > 0; off >>= 1) s += __shfl_down(s, off);
  if (lane == 0) t3[wid] = s;
}

__global__ void final_kernel(const float* __restrict__ t3, const int* __restrict__ rowptr,
                             const int* __restrict__ csr, const float* __restrict__ csr_w,
                             const float* __restrict__ dinv, const float* __restrict__ b3,
                             float* __restrict__ out, int n) {
  int d = blockIdx.x * blockDim.x + threadIdx.x;
  if (d >= n) return;
  float acc = 0.f;
  int beg = rowptr[d], end = rowptr[d + 1];
  for (int j = beg; j < end; ++j) acc += csr_w[j] * t3[csr[j]];
  float di = dinv[d];
  out[d] = acc * di + t3[d] * di * di + b3[0];
}

// ---------------- launcher ----------------

extern "C" void kernel_launch(void* const* d_in, const int* in_sizes, int n_in,
                              void* d_out, int out_size, void* d_ws, size_t ws_size,
                              hipStream_t stream) {
  const float* x   = (const float*)d_in[0];
  const int* src   = (const int*)d_in[1];
  const int* dst   = (const int*)d_in[2];
  const int* batch = (const int*)d_in[3];
  const float* W0 = (const float*)d_in[4];
  const float* b0 = (const float*)d_in[5];
  const float* Wf = (const float*)d_in[6];
  const float* bf = (const float*)d_in[7];
  const float* W1 = (const float*)d_in[8];
  const float* b1 = (const float*)d_in[9];
  const float* W2 = (const float*)d_in[10];
  const float* b2 = (const float*)d_in[11];
  const float* W3 = (const float*)d_in[12];
  const float* b3 = (const float*)d_in[13];
  float* out = (float*)d_out;

  char* p = (char*)d_ws;
  auto alloc = [&](size_t bytes) { char* q = p; p += (bytes + 255) & ~(size_t)255; return q; };
  float* bufA   = (float*)alloc((size_t)N_NODES * HID * 4);
  float* bufB   = (float*)alloc((size_t)N_NODES * HID * 4);
  int*   cnt    = (int*)alloc((size_t)N_NODES * 4);
  int*   rowptr = (int*)alloc((size_t)(N_NODES + 1) * 4);
  int*   cursor = (int*)alloc((size_t)N_NODES * 4);
  int*   csr    = (int*)alloc((size_t)N_EDGES * 4);
  float* csrw   = (float*)alloc((size_t)N_EDGES * 4);
  float* dinv   = (float*)alloc((size_t)N_NODES * 4);
  int*   bounds = (int*)alloc(256 * 4);
  float* gi2    = (float*)alloc((size_t)N_GRAPHS * HID * 4);
  float* t3     = (float*)alloc((size_t)N_NODES * 4);

  hipMemsetAsync(cnt, 0, (size_t)N_NODES * 4, stream);
  hipMemsetAsync(cursor, 0, (size_t)N_NODES * 4, stream);

  int eb = (N_EDGES + 255) / 256;
  int nb = (N_NODES + 255) / 256;
  hist_kernel<<<eb, 256, 0, stream>>>(dst, cnt, N_EDGES);
  dinv_kernel<<<nb, 256, 0, stream>>>(cnt, dinv, N_NODES);
  scan_kernel<<<1, 1024, 0, stream>>>(cnt, rowptr, N_NODES);
  place_kernel<<<eb, 256, 0, stream>>>(dst, rowptr, cursor, csr, N_EDGES);
  sortrow_kernel<<<nb, 256, 0, stream>>>(csr, csrw, rowptr, src, dinv, N_NODES);
  bounds_kernel<<<1, 128, 0, stream>>>(batch, bounds, N_NODES, N_GRAPHS);

  int gb = (N_NODES + BM - 1) / BM;

  // conv0 (pre-agg 128-wide): Z0 = agg(x) -> bufA ; h0 = relu(Z0@W0+b0) -> bufB
  agg_kernel<FEAT, false, false><<<N_NODES, FEAT, 0, stream>>>(x, rowptr, csr, csrw, dinv, nullptr, bufA);
  gemm_kernel<FEAT, true, true, false><<<gb, 256, 0, stream>>>(bufA, W0, b0, nullptr, nullptr, bufB, N_NODES);

  // pooled -> fc1 -> @W2b, fused: gi2[64x256]
  poolfc_kernel<<<N_GRAPHS, HID, 0, stream>>>(bufB, bounds, Wf, bf, W2, gi2);

  // conv1 #1: Z1 = agg(h0) -> bufA ; loc1 = relu(Z1@W1+b1) -> bufB
  agg_kernel<HID, false, false><<<N_NODES, HID, 0, stream>>>(bufB, rowptr, csr, csrw, dinv, nullptr, bufA);
  gemm_kernel<HID, true, true, false><<<gb, 256, 0, stream>>>(bufA, W1, b1, nullptr, nullptr, bufB, N_NODES);

  // conv1 #2: Z2 = agg(loc1) -> bufA ; loc2 = relu(Z2@W1+b1) -> bufB
  agg_kernel<HID, false, false><<<N_NODES, HID, 0, stream>>>(bufB, rowptr, csr, csrw, dinv, nullptr, bufA);
  gemm_kernel<HID, true, true, false><<<gb, 256, 0, stream>>>(bufA, W1, b1, nullptr, nullptr, bufB, N_NODES);

  // conv2 (post-agg): T2 = loc2@W2a + gi2[batch] -> bufA ; h2 = relu(agg(T2)+b2) -> bufB
  gemm_kernel<HID, false, false, true><<<gb, 256, 0, stream>>>(bufB, W2, nullptr, gi2, batch, bufA, N_NODES);
  agg_kernel<HID, true, true><<<N_NODES, HID, 0, stream>>>(bufA, rowptr, csr, csrw, dinv, b2, bufB);

  // conv3 (post-agg, width 1): t3 = h2@W3 ; logits = agg_scalar(t3)+b3 -> out
  dot_kernel<<<(N_NODES * 64 + 255) / 256, 256, 0, stream>>>(bufB, W3, t3, N_NODES);
  final_kernel<<<nb, 256, 0, stream>>>(t3, rowptr, csr, csrw, dinv, b3, out, N_NODES);
}

// Round 2
// 722.201 us; speedup vs baseline: 2.0074x; 2.0074x over previous
//
#include <hip/hip_runtime.h>
#include <type_traits>

#define N_NODES 50000
#define N_EDGES 800000
#define FEAT 128
#define HID 256
#define N_GRAPHS 64

typedef float floatx4 __attribute__((ext_vector_type(4)));
typedef _Float16 half2_t __attribute__((ext_vector_type(2)));
typedef _Float16 half4_t __attribute__((ext_vector_type(4)));
typedef _Float16 half8_t __attribute__((ext_vector_type(8)));

// ---------------- graph preprocessing ----------------

__global__ void hist_kernel(const int* __restrict__ dst, int* __restrict__ cnt, int e) {
  int i = blockIdx.x * blockDim.x + threadIdx.x;
  if (i < e) atomicAdd(&cnt[dst[i]], 1);
}

__global__ void dinv_kernel(const int* __restrict__ cnt, float* __restrict__ dinv, int n) {
  int i = blockIdx.x * blockDim.x + threadIdx.x;
  if (i < n) dinv[i] = 1.0f / sqrtf((float)cnt[i] + 1.0f);
}

__global__ void scan_kernel(const int* __restrict__ cnt, int* __restrict__ rowptr, int n) {
  __shared__ int part[1024];
  int tid = threadIdx.x;
  int per = (n + 1023) >> 10;
  int beg = min(tid * per, n), end = min(beg + per, n);
  int s = 0;
  for (int i = beg; i < end; ++i) s += cnt[i];
  part[tid] = s;
  __syncthreads();
  for (int off = 1; off < 1024; off <<= 1) {
    int v = (tid >= off) ? part[tid - off] : 0;
    __syncthreads();
    part[tid] += v;
    __syncthreads();
  }
  int run = (tid == 0) ? 0 : part[tid - 1];
  for (int i = beg; i < end; ++i) { rowptr[i] = run; run += cnt[i]; }
  if (tid == 1023) rowptr[n] = run;
}

__global__ void place_kernel(const int* __restrict__ dst, const int* __restrict__ rowptr,
                             int* __restrict__ cursor, int* __restrict__ csr, int e) {
  int i = blockIdx.x * blockDim.x + threadIdx.x;
  if (i < e) {
    int d = dst[i];
    int slot = rowptr[d] + atomicAdd(&cursor[d], 1);
    csr[slot] = i;  // edge id, sorted per-row later for determinism
  }
}

__global__ void sortrow_kernel(int* __restrict__ csr, float* __restrict__ csr_w,
                               const int* __restrict__ rowptr, const int* __restrict__ src,
                               const float* __restrict__ dinv, int n) {
  int d = blockIdx.x * blockDim.x + threadIdx.x;
  if (d >= n) return;
  int beg = rowptr[d], len = rowptr[d + 1] - beg;
  if (len <= 64) {
    int buf[64];
    for (int j = 0; j < len; ++j) buf[j] = csr[beg + j];
    for (int j = 1; j < len; ++j) {
      int v = buf[j]; int k = j - 1;
      while (k >= 0 && buf[k] > v) { buf[k + 1] = buf[k]; --k; }
      buf[k + 1] = v;
    }
    for (int j = 0; j < len; ++j) {
      int s = src[buf[j]];
      csr[beg + j] = s; csr_w[beg + j] = dinv[s];
    }
  } else {
    for (int j = 0; j < len; ++j) {
      int s = src[csr[beg + j]];
      csr[beg + j] = s; csr_w[beg + j] = dinv[s];
    }
  }
}

__global__ void bounds_kernel(const int* __restrict__ batch, int* __restrict__ bounds,
                              int n, int g) {
  int t = threadIdx.x;
  if (t > g) return;
  int lo = 0, hi = n;
  while (lo < hi) { int mid = (lo + hi) >> 1; if (batch[mid] < t) lo = mid + 1; else hi = mid; }
  bounds[t] = lo;
}

// ---------------- conversions ----------------

__global__ void xcvt_kernel(const float* __restrict__ x, _Float16* __restrict__ xh, int n4) {
  int i = blockIdx.x * blockDim.x + threadIdx.x;
  if (i >= n4) return;
  floatx4 v = ((const floatx4*)x)[i];
  half4_t h;
  h[0] = (_Float16)v[0]; h[1] = (_Float16)v[1];
  h[2] = (_Float16)v[2]; h[3] = (_Float16)v[3];
  ((half4_t*)xh)[i] = h;
}

// Bt[c][k] = (f16) W[k][c]   (W is [K][256] f32; Bt is [256][K] f16)
__global__ void wcvt_kernel(const float* __restrict__ W, _Float16* __restrict__ Bt, int K) {
  int idx = blockIdx.x * blockDim.x + threadIdx.x;
  if (idx >= K * 256) return;
  int c = idx / K, k = idx - c * K;
  Bt[idx] = (_Float16)W[k * 256 + c];
}

// ---------------- aggregation (f16 in/out, f32 accumulate) ----------------
// out[d] = dinv[d]*sum_j w_j*T[s_j] + T[d]*dinv[d]^2 (+bias)(relu)
// one wave per destination node; EPL f16 per lane (EPL=2 -> 128-wide, 4 -> 256-wide)
template <int EPL, bool BIAS, bool RELU>
__global__ __launch_bounds__(256) void agg16_kernel(
    const _Float16* __restrict__ T, const int* __restrict__ rowptr,
    const int* __restrict__ csr, const float* __restrict__ csr_w,
    const float* __restrict__ dinv, const float* __restrict__ bias,
    _Float16* __restrict__ out, int n) {
  using hvec = typename std::conditional<EPL == 2, half2_t, half4_t>::type;
  int lane = threadIdx.x & 63;
  int d = (blockIdx.x << 2) + (threadIdx.x >> 6);
  if (d >= n) return;
  const hvec* Tv = (const hvec*)T;  // 64 lanes x EPL = row
  int beg = rowptr[d], end = rowptr[d + 1];
  float acc[EPL];
  #pragma unroll
  for (int e = 0; e < EPL; ++e) acc[e] = 0.f;
  int j = beg;
  for (; j + 2 <= end; j += 2) {   // 2 rows in flight per lane
    int s0 = csr[j], s1 = csr[j + 1];
    float w0 = csr_w[j], w1 = csr_w[j + 1];
    hvec v0 = Tv[(size_t)s0 * 64 + lane];
    hvec v1 = Tv[(size_t)s1 * 64 + lane];
    #pragma unroll
    for (int e = 0; e < EPL; ++e) acc[e] += w0 * (float)v0[e] + w1 * (float)v1[e];
  }
  if (j < end) {
    int s0 = csr[j]; float w0 = csr_w[j];
    hvec v0 = Tv[(size_t)s0 * 64 + lane];
    #pragma unroll
    for (int e = 0; e < EPL; ++e) acc[e] += w0 * (float)v0[e];
  }
  float di = dinv[d];
  hvec vs = Tv[(size_t)d * 64 + lane];
  hvec o;
  #pragma unroll
  for (int e = 0; e < EPL; ++e) {
    float v = acc[e] * di + (float)vs[e] * di * di;
    if (BIAS) v += bias[lane * EPL + e];
    if (RELU) v = fmaxf(v, 0.f);
    o[e] = (_Float16)v;
  }
  ((hvec*)out)[(size_t)d * 64 + lane] = o;
}

// ---------------- MFMA GEMM: C[N x 256] = A[N x K] @ B[K x 256] ----------------
// A f16 row-major, Bt f16 [col][K]; f32 accum; epilogue bias/gi2/relu; f16 out.
// Block = 256 threads = 4 waves; wave owns 32 rows x 256 cols.
// Operand-swapped mfma(wb, xa, acc): lane's 4 acc elems = 4 consecutive C cols.
template <int K, bool BIAS, bool RELU, bool GIADD>
__global__ __launch_bounds__(256) void mfma_gemm(
    const _Float16* __restrict__ A, const _Float16* __restrict__ Bt,
    const float* __restrict__ bias, const float* __restrict__ gi2,
    const int* __restrict__ batch, _Float16* __restrict__ C, int nrows) {
  int lane = threadIdx.x & 63;
  int wv = threadIdx.x >> 6;
  int rlo = lane & 15, khi = lane >> 4;
  int row0 = blockIdx.x * 128 + wv * 32;
  floatx4 acc[2][16];
  #pragma unroll
  for (int h = 0; h < 2; ++h)
    #pragma unroll
    for (int g = 0; g < 16; ++g)
      { acc[h][g][0] = 0.f; acc[h][g][1] = 0.f; acc[h][g][2] = 0.f; acc[h][g][3] = 0.f; }

  int ra0 = min(row0 + rlo, nrows - 1);
  int ra1 = min(row0 + 16 + rlo, nrows - 1);
  for (int kc = 0; kc < K; kc += 32) {
    int kof = kc + khi * 8;
    half8_t xa0 = *(const half8_t*)(A + (size_t)ra0 * K + kof);
    half8_t xa1 = *(const half8_t*)(A + (size_t)ra1 * K + kof);
    #pragma unroll
    for (int g = 0; g < 16; ++g) {
      half8_t wb = *(const half8_t*)(Bt + (size_t)(g * 16 + rlo) * K + kof);
      acc[0][g] = __builtin_amdgcn_mfma_f32_16x16x32_f16(wb, xa0, acc[0][g], 0, 0, 0);
      acc[1][g] = __builtin_amdgcn_mfma_f32_16x16x32_f16(wb, xa1, acc[1][g], 0, 0, 0);
    }
  }
  #pragma unroll
  for (int h = 0; h < 2; ++h) {
    int crow = row0 + h * 16 + rlo;
    if (crow >= nrows) continue;
    const float* gp = nullptr;
    if (GIADD) gp = gi2 + (size_t)batch[crow] * HID;
    #pragma unroll
    for (int g = 0; g < 16; ++g) {
      int c0 = g * 16 + khi * 4;
      floatx4 v = acc[h][g];
      if (BIAS) v += *(const floatx4*)(bias + c0);
      if (GIADD) v += *(const floatx4*)(gp + c0);
      if (RELU) {
        v[0] = fmaxf(v[0], 0.f); v[1] = fmaxf(v[1], 0.f);
        v[2] = fmaxf(v[2], 0.f); v[3] = fmaxf(v[3], 0.f);
      }
      half4_t hv;
      hv[0] = (_Float16)v[0]; hv[1] = (_Float16)v[1];
      hv[2] = (_Float16)v[2]; hv[3] = (_Float16)v[3];
      *(half4_t*)(C + (size_t)crow * HID + c0) = hv;
    }
  }
}

// ---------------- fused pool -> fc1 -> @W2[256:512] ----------------
__global__ __launch_bounds__(1024) void poolfc_kernel(
    const _Float16* __restrict__ h0, const int* __restrict__ bounds,
    const float* __restrict__ Wf, const float* __restrict__ bf,
    const float* __restrict__ W2, float* __restrict__ gi2) {
  __shared__ float R[4][HID];
  __shared__ float P[HID];
  __shared__ float GI[HID];
  int g = blockIdx.x;
  int tid = threadIdx.x;
  int rg = tid >> 8, c = tid & 255;
  int beg = bounds[g], end = bounds[g + 1];
  float m = -INFINITY;
  for (int i = beg + rg; i < end; i += 4) m = fmaxf(m, (float)h0[(size_t)i * HID + c]);
  R[rg][c] = m;
  __syncthreads();
  if (rg == 0) P[c] = fmaxf(fmaxf(R[0][c], R[1][c]), fmaxf(R[2][c], R[3][c]));
  __syncthreads();
  if (rg == 0) {
    float a = 0.f;
    for (int k = 0; k < HID; ++k) a += P[k] * Wf[k * HID + c];
    GI[c] = a + bf[c];
  }
  __syncthreads();
  if (rg == 0) {
    float a = 0.f;
    for (int k = 0; k < HID; ++k) a += GI[k] * W2[(HID + k) * HID + c];
    gi2[g * HID + c] = a;
  }
}

// ---------------- conv3 width-1 path ----------------
__global__ void dot16_kernel(const _Float16* __restrict__ H, const float* __restrict__ W3,
                             float* __restrict__ t3, int n) {
  int gt = blockIdx.x * blockDim.x + threadIdx.x;
  int wid = gt >> 6, lane = gt & 63;
  if (wid >= n) return;
  half4_t h = ((const half4_t*)H)[(size_t)wid * 64 + lane];
  floatx4 w = ((const floatx4*)W3)[lane];
  float s = (float)h[0] * w[0] + (float)h[1] * w[1] + (float)h[2] * w[2] + (float)h[3] * w[3];
  for (int off = 32; off > 0; off >>= 1) s += __shfl_down(s, off);
  if (lane == 0) t3[wid] = s;
}

__global__ void final_kernel(const float* __restrict__ t3, const int* __restrict__ rowptr,
                             const int* __restrict__ csr, const float* __restrict__ csr_w,
                             const float* __restrict__ dinv, const float* __restrict__ b3,
                             float* __restrict__ out, int n) {
  int d = blockIdx.x * blockDim.x + threadIdx.x;
  if (d >= n) return;
  float acc = 0.f;
  int beg = rowptr[d], end = rowptr[d + 1];
  for (int j = beg; j < end; ++j) acc += csr_w[j] * t3[csr[j]];
  float di = dinv[d];
  out[d] = acc * di + t3[d] * di * di + b3[0];
}

// ---------------- launcher ----------------

extern "C" void kernel_launch(void* const* d_in, const int* in_sizes, int n_in,
                              void* d_out, int out_size, void* d_ws, size_t ws_size,
                              hipStream_t stream) {
  const float* x   = (const float*)d_in[0];
  const int* src   = (const int*)d_in[1];
  const int* dst   = (const int*)d_in[2];
  const int* batch = (const int*)d_in[3];
  const float* W0 = (const float*)d_in[4];
  const float* b0 = (const float*)d_in[5];
  const float* Wf = (const float*)d_in[6];
  const float* bf = (const float*)d_in[7];
  const float* W1 = (const float*)d_in[8];
  const float* b1 = (const float*)d_in[9];
  const float* W2 = (const float*)d_in[10];
  const float* b2 = (const float*)d_in[11];
  const float* W3 = (const float*)d_in[12];
  const float* b3 = (const float*)d_in[13];
  float* out = (float*)d_out;

  char* p = (char*)d_ws;
  auto alloc = [&](size_t bytes) { char* q = p; p += (bytes + 255) & ~(size_t)255; return q; };
  _Float16* hA   = (_Float16*)alloc((size_t)N_NODES * HID * 2);
  _Float16* hB   = (_Float16*)alloc((size_t)N_NODES * HID * 2);
  _Float16* xh   = (_Float16*)alloc((size_t)N_NODES * FEAT * 2);
  _Float16* W0t  = (_Float16*)alloc((size_t)HID * FEAT * 2);
  _Float16* W1t  = (_Float16*)alloc((size_t)HID * HID * 2);
  _Float16* W2at = (_Float16*)alloc((size_t)HID * HID * 2);
  int*   cnt    = (int*)alloc((size_t)N_NODES * 4);
  int*   rowptr = (int*)alloc((size_t)(N_NODES + 1) * 4);
  int*   cursor = (int*)alloc((size_t)N_NODES * 4);
  int*   csr    = (int*)alloc((size_t)N_EDGES * 4);
  float* csrw   = (float*)alloc((size_t)N_EDGES * 4);
  float* dinv   = (float*)alloc((size_t)N_NODES * 4);
  int*   bounds = (int*)alloc(256 * 4);
  float* gi2    = (float*)alloc((size_t)N_GRAPHS * HID * 4);
  float* t3     = (float*)alloc((size_t)N_NODES * 4);

  hipMemsetAsync(cnt, 0, (size_t)N_NODES * 4, stream);
  hipMemsetAsync(cursor, 0, (size_t)N_NODES * 4, stream);

  int eb = (N_EDGES + 255) / 256;
  int nb = (N_NODES + 255) / 256;

  // conversions (independent of graph preproc)
  xcvt_kernel<<<(N_NODES * FEAT / 4 + 255) / 256, 256, 0, stream>>>(x, xh, N_NODES * FEAT / 4);
  wcvt_kernel<<<(FEAT * 256 + 255) / 256, 256, 0, stream>>>(W0, W0t, FEAT);
  wcvt_kernel<<<(HID * 256 + 255) / 256, 256, 0, stream>>>(W1, W1t, HID);
  wcvt_kernel<<<(HID * 256 + 255) / 256, 256, 0, stream>>>(W2, W2at, HID);

  hist_kernel<<<eb, 256, 0, stream>>>(dst, cnt, N_EDGES);
  dinv_kernel<<<nb, 256, 0, stream>>>(cnt, dinv, N_NODES);
  scan_kernel<<<1, 1024, 0, stream>>>(cnt, rowptr, N_NODES);
  place_kernel<<<eb, 256, 0, stream>>>(dst, rowptr, cursor, csr, N_EDGES);
  sortrow_kernel<<<nb, 256, 0, stream>>>(csr, csrw, rowptr, src, dinv, N_NODES);
  bounds_kernel<<<1, 128, 0, stream>>>(batch, bounds, N_NODES, N_GRAPHS);

  int ab = 12500;                       // 4 nodes / block
  int gb = (N_NODES + 127) / 128;       // 391 row-tiles

  // conv0: Z0 = agg(xh) [N,128] -> hA ; h0 = relu(Z0@W0+b0) -> hB
  agg16_kernel<2, false, false><<<ab, 256, 0, stream>>>(xh, rowptr, csr, csrw, dinv, nullptr, hA, N_NODES);
  mfma_gemm<FEAT, true, true, false><<<gb, 256, 0, stream>>>(hA, W0t, b0, nullptr, nullptr, hB, N_NODES);

  // gi2 = (max-pool(h0) @ Wf + bf) @ W2[256:512]
  poolfc_kernel<<<N_GRAPHS, 1024, 0, stream>>>(hB, bounds, Wf, bf, W2, gi2);

  // conv1 #1
  agg16_kernel<4, false, false><<<ab, 256, 0, stream>>>(hB, rowptr, csr, csrw, dinv, nullptr, hA, N_NODES);
  mfma_gemm<HID, true, true, false><<<gb, 256, 0, stream>>>(hA, W1t, b1, nullptr, nullptr, hB, N_NODES);

  // conv1 #2
  agg16_kernel<4, false, false><<<ab, 256, 0, stream>>>(hB, rowptr, csr, csrw, dinv, nullptr, hA, N_NODES);
  mfma_gemm<HID, true, true, false><<<gb, 256, 0, stream>>>(hA, W1t, b1, nullptr, nullptr, hB, N_NODES);

  // conv2: T2 = loc2@W2a + gi2[batch] -> hA ; h2 = relu(agg(T2)+b2) -> hB
  mfma_gemm<HID, false, false, true><<<gb, 256, 0, stream>>>(hB, W2at, nullptr, gi2, batch, hA, N_NODES);
  agg16_kernel<4, true, true><<<ab, 256, 0, stream>>>(hA, rowptr, csr, csrw, dinv, b2, hB, N_NODES);

  // conv3: t3 = h2@W3 ; logits = agg_scalar(t3) + b3
  dot16_kernel<<<(N_NODES * 64 + 255) / 256, 256, 0, stream>>>(hB, W3, t3, N_NODES);
  final_kernel<<<nb, 256, 0, stream>>>(t3, rowptr, csr, csrw, dinv, b3, out, N_NODES);
}

// Round 3
// 556.934 us; speedup vs baseline: 2.6031x; 1.2967x over previous
//
#include <hip/hip_runtime.h>

#define N_NODES 50000
#define N_EDGES 800000
#define FEAT 128
#define HID 256
#define N_GRAPHS 64
#define NB_SCAN ((N_NODES + 255) / 256)
#define POOL_SPLIT 8

typedef float floatx4 __attribute__((ext_vector_type(4)));
typedef _Float16 half4_t __attribute__((ext_vector_type(4)));
typedef _Float16 half8_t __attribute__((ext_vector_type(8)));

// ---------------- graph preprocessing ----------------

__global__ void hist_kernel(const int* __restrict__ dst, int* __restrict__ cnt, int e) {
  int i = blockIdx.x * blockDim.x + threadIdx.x;
  if (i < e) atomicAdd(&cnt[dst[i]], 1);
}

// pass 1: per-block sum of cnt + dinv computation (fused)
__global__ __launch_bounds__(256) void scan1_kernel(const int* __restrict__ cnt,
                                                    float* __restrict__ dinv,
                                                    int* __restrict__ bsum, int n) {
  __shared__ int sh[256];
  int i = blockIdx.x * 256 + threadIdx.x;
  int c = (i < n) ? cnt[i] : 0;
  if (i < n) dinv[i] = 1.0f / sqrtf((float)c + 1.0f);
  sh[threadIdx.x] = c;
  __syncthreads();
  for (int off = 128; off > 0; off >>= 1) {
    if (threadIdx.x < off) sh[threadIdx.x] += sh[threadIdx.x + off];
    __syncthreads();
  }
  if (threadIdx.x == 0) bsum[blockIdx.x] = sh[0];
}

// pass 2: scan the block sums (one 256-thread block; NB_SCAN <= 256)
__global__ __launch_bounds__(256) void scan2_kernel(const int* __restrict__ bsum,
                                                    int* __restrict__ boff,
                                                    int* __restrict__ rowptr) {
  __shared__ int sh[256];
  int t = threadIdx.x;
  int v = (t < NB_SCAN) ? bsum[t] : 0;
  sh[t] = v;
  __syncthreads();
  for (int off = 1; off < 256; off <<= 1) {
    int u = (t >= off) ? sh[t - off] : 0;
    __syncthreads();
    sh[t] += u;
    __syncthreads();
  }
  if (t < NB_SCAN) boff[t] = (t == 0) ? 0 : sh[t - 1];
  if (t == 255) rowptr[N_NODES] = sh[255];
}

// pass 3: per-block exclusive scan + offset -> rowptr
__global__ __launch_bounds__(256) void scan3_kernel(const int* __restrict__ cnt,
                                                    const int* __restrict__ boff,
                                                    int* __restrict__ rowptr, int n) {
  __shared__ int sh[256];
  int i = blockIdx.x * 256 + threadIdx.x;
  int c = (i < n) ? cnt[i] : 0;
  sh[threadIdx.x] = c;
  __syncthreads();
  for (int off = 1; off < 256; off <<= 1) {
    int u = (threadIdx.x >= off) ? sh[threadIdx.x - off] : 0;
    __syncthreads();
    sh[threadIdx.x] += u;
    __syncthreads();
  }
  if (i < n) rowptr[i] = boff[blockIdx.x] + sh[threadIdx.x] - c;
}

__global__ void place_kernel(const int* __restrict__ dst, const int* __restrict__ rowptr,
                             int* __restrict__ cursor, int* __restrict__ csr, int e) {
  int i = blockIdx.x * blockDim.x + threadIdx.x;
  if (i < e) {
    int d = dst[i];
    int slot = rowptr[d] + atomicAdd(&cursor[d], 1);
    csr[slot] = i;  // edge id; canonical per-row order established below
  }
}

// one wave per row: bitonic sort of edge ids (deterministic canonical order),
// then rewrite slot as (src, dinv[src])
__global__ __launch_bounds__(256) void sortrow_kernel(
    int* __restrict__ csr, float* __restrict__ csr_w, const int* __restrict__ rowptr,
    const int* __restrict__ src, const float* __restrict__ dinv, int n) {
  int wid = (blockIdx.x * 256 + threadIdx.x) >> 6;
  int lane = threadIdx.x & 63;
  if (wid >= n) return;
  int beg = rowptr[wid], len = rowptr[wid + 1] - beg;
  if (len <= 64) {
    int v = (lane < len) ? csr[beg + lane] : 0x7fffffff;
    #pragma unroll
    for (int k = 2; k <= 64; k <<= 1) {
      #pragma unroll
      for (int j = k >> 1; j >= 1; j >>= 1) {
        int other = __shfl_xor(v, j);
        int mn = min(v, other), mx = max(v, other);
        bool up = (lane & k) == 0;
        v = (((lane & j) == 0) == up) ? mn : mx;
      }
    }
    if (lane < len) {
      int s = src[v];
      csr[beg + lane] = s;
      csr_w[beg + lane] = dinv[s];
    }
  } else if (lane == 0) {  // Poisson(16): unreachable in practice, correct anyway
    for (int a = 0; a < len; ++a)
      for (int b = a + 1; b < len; ++b) {
        int xa = csr[beg + a], xb = csr[beg + b];
        if (xb < xa) { csr[beg + a] = xb; csr[beg + b] = xa; }
      }
    for (int a = 0; a < len; ++a) {
      int s = src[csr[beg + a]];
      csr[beg + a] = s;
      csr_w[beg + a] = dinv[s];
    }
  }
}

__global__ void bounds_kernel(const int* __restrict__ batch, int* __restrict__ bounds,
                              int n, int g) {
  int t = threadIdx.x;
  if (t > g) return;
  int lo = 0, hi = n;
  while (lo < hi) { int mid = (lo + hi) >> 1; if (batch[mid] < t) lo = mid + 1; else hi = mid; }
  bounds[t] = lo;
}

// ---------------- conversions ----------------

__global__ void xcvt_kernel(const float* __restrict__ x, _Float16* __restrict__ xh, int n4) {
  int i = blockIdx.x * blockDim.x + threadIdx.x;
  if (i >= n4) return;
  floatx4 v = ((const floatx4*)x)[i];
  half4_t h;
  h[0] = (_Float16)v[0]; h[1] = (_Float16)v[1];
  h[2] = (_Float16)v[2]; h[3] = (_Float16)v[3];
  ((half4_t*)xh)[i] = h;
}

// Bt[c][k] = (f16) W[k][c]
__global__ void wcvt_kernel(const float* __restrict__ W, _Float16* __restrict__ Bt, int K) {
  int idx = blockIdx.x * blockDim.x + threadIdx.x;
  if (idx >= K * 256) return;
  int c = idx / K, k = idx - c * K;
  Bt[idx] = (_Float16)W[k * 256 + c];
}

// ---------------- aggregation (f16 in/out, f32 accumulate) ----------------
// out[d] = dinv[d]*sum_j w_j*T[s_j] + T[d]*dinv[d]^2 (+bias)(relu)
// F/8 lanes per row, 16B loads, 4 edges in flight.
template <int F, bool BIAS, bool RELU>
__global__ __launch_bounds__(256) void agg16_kernel(
    const _Float16* __restrict__ T, const int* __restrict__ rowptr,
    const int* __restrict__ csr, const float* __restrict__ csr_w,
    const float* __restrict__ dinv, const float* __restrict__ bias,
    _Float16* __restrict__ out, int n) {
  constexpr int LPR = F / 8;         // lanes per row
  constexpr int RPB = 256 / LPR;     // rows per block
  int li = threadIdx.x & (LPR - 1);
  int d = blockIdx.x * RPB + threadIdx.x / LPR;
  if (d >= n) return;
  const half8_t* Tv = (const half8_t*)T;
  int beg = rowptr[d], end = rowptr[d + 1];
  float acc[8];
  #pragma unroll
  for (int e = 0; e < 8; ++e) acc[e] = 0.f;
  int j = beg;
  for (; j + 4 <= end; j += 4) {
    int s0 = csr[j], s1 = csr[j + 1], s2 = csr[j + 2], s3 = csr[j + 3];
    float w0 = csr_w[j], w1 = csr_w[j + 1], w2 = csr_w[j + 2], w3 = csr_w[j + 3];
    half8_t v0 = Tv[(size_t)s0 * LPR + li];
    half8_t v1 = Tv[(size_t)s1 * LPR + li];
    half8_t v2 = Tv[(size_t)s2 * LPR + li];
    half8_t v3 = Tv[(size_t)s3 * LPR + li];
    #pragma unroll
    for (int e = 0; e < 8; ++e)
      acc[e] += w0 * (float)v0[e] + w1 * (float)v1[e] + w2 * (float)v2[e] + w3 * (float)v3[e];
  }
  for (; j < end; ++j) {
    int s0 = csr[j];
    float w0 = csr_w[j];
    half8_t v0 = Tv[(size_t)s0 * LPR + li];
    #pragma unroll
    for (int e = 0; e < 8; ++e) acc[e] += w0 * (float)v0[e];
  }
  float di = dinv[d];
  half8_t vs = Tv[(size_t)d * LPR + li];
  half8_t o;
  #pragma unroll
  for (int e = 0; e < 8; ++e) {
    float v = acc[e] * di + (float)vs[e] * di * di;
    if (BIAS) v += bias[li * 8 + e];
    if (RELU) v = fmaxf(v, 0.f);
    o[e] = (_Float16)v;
  }
  ((half8_t*)out)[(size_t)d * LPR + li] = o;
}

// ---------------- MFMA GEMM: C[N x 256] = A[N x K] @ Bt^T ----------------
template <int K, bool BIAS, bool RELU, bool GIADD>
__global__ __launch_bounds__(256) void mfma_gemm(
    const _Float16* __restrict__ A, const _Float16* __restrict__ Bt,
    const float* __restrict__ bias, const float* __restrict__ gi2,
    const int* __restrict__ batch, _Float16* __restrict__ C, int nrows) {
  int lane = threadIdx.x & 63;
  int wv = threadIdx.x >> 6;
  int rlo = lane & 15, khi = lane >> 4;
  int row0 = blockIdx.x * 128 + wv * 32;
  floatx4 acc[2][16];
  #pragma unroll
  for (int h = 0; h < 2; ++h)
    #pragma unroll
    for (int g = 0; g < 16; ++g)
      { acc[h][g][0] = 0.f; acc[h][g][1] = 0.f; acc[h][g][2] = 0.f; acc[h][g][3] = 0.f; }

  int ra0 = min(row0 + rlo, nrows - 1);
  int ra1 = min(row0 + 16 + rlo, nrows - 1);
  for (int kc = 0; kc < K; kc += 32) {
    int kof = kc + khi * 8;
    half8_t xa0 = *(const half8_t*)(A + (size_t)ra0 * K + kof);
    half8_t xa1 = *(const half8_t*)(A + (size_t)ra1 * K + kof);
    #pragma unroll
    for (int g = 0; g < 16; ++g) {
      half8_t wb = *(const half8_t*)(Bt + (size_t)(g * 16 + rlo) * K + kof);
      acc[0][g] = __builtin_amdgcn_mfma_f32_16x16x32_f16(wb, xa0, acc[0][g], 0, 0, 0);
      acc[1][g] = __builtin_amdgcn_mfma_f32_16x16x32_f16(wb, xa1, acc[1][g], 0, 0, 0);
    }
  }
  #pragma unroll
  for (int h = 0; h < 2; ++h) {
    int crow = row0 + h * 16 + rlo;
    if (crow >= nrows) continue;
    const float* gp = nullptr;
    if (GIADD) gp = gi2 + (size_t)batch[crow] * HID;
    #pragma unroll
    for (int g = 0; g < 16; ++g) {
      int c0 = g * 16 + khi * 4;
      floatx4 v = acc[h][g];
      if (BIAS) v += *(const floatx4*)(bias + c0);
      if (GIADD) v += *(const floatx4*)(gp + c0);
      if (RELU) {
        v[0] = fmaxf(v[0], 0.f); v[1] = fmaxf(v[1], 0.f);
        v[2] = fmaxf(v[2], 0.f); v[3] = fmaxf(v[3], 0.f);
      }
      half4_t hv;
      hv[0] = (_Float16)v[0]; hv[1] = (_Float16)v[1];
      hv[2] = (_Float16)v[2]; hv[3] = (_Float16)v[3];
      *(half4_t*)(C + (size_t)crow * HID + c0) = hv;
    }
  }
}

// ---------------- pooling (split) -> fc1 -> @W2[256:512] ----------------

__global__ __launch_bounds__(256) void pool1_kernel(const _Float16* __restrict__ h0,
                                                    const int* __restrict__ bounds,
                                                    float* __restrict__ Ppart) {
  int g = blockIdx.x / POOL_SPLIT, s = blockIdx.x % POOL_SPLIT;
  int c = threadIdx.x;
  int beg = bounds[g], end = bounds[g + 1];
  float m = -INFINITY;
  for (int i = beg + s; i < end; i += POOL_SPLIT)
    m = fmaxf(m, (float)h0[(size_t)i * HID + c]);
  Ppart[(size_t)(g * POOL_SPLIT + s) * HID + c] = m;
}

__global__ __launch_bounds__(256) void pool2_kernel(const float* __restrict__ Ppart,
                                                    const float* __restrict__ Wf,
                                                    const float* __restrict__ bf,
                                                    const float* __restrict__ W2,
                                                    float* __restrict__ gi2) {
  __shared__ float P[HID];
  __shared__ float GI[HID];
  int g = blockIdx.x;
  int c = threadIdx.x;
  float m = -INFINITY;
  #pragma unroll
  for (int s = 0; s < POOL_SPLIT; ++s)
    m = fmaxf(m, Ppart[(size_t)(g * POOL_SPLIT + s) * HID + c]);
  P[c] = m;
  __syncthreads();
  float a = 0.f;
  for (int k = 0; k < HID; ++k) a += P[k] * Wf[k * HID + c];
  GI[c] = a + bf[c];
  __syncthreads();
  float a2 = 0.f;
  for (int k = 0; k < HID; ++k) a2 += GI[k] * W2[(HID + k) * HID + c];
  gi2[g * HID + c] = a2;
}

// ---------------- conv3 width-1 path ----------------
__global__ void dot16_kernel(const _Float16* __restrict__ H, const float* __restrict__ W3,
                             float* __restrict__ t3, int n) {
  int gt = blockIdx.x * blockDim.x + threadIdx.x;
  int wid = gt >> 6, lane = gt & 63;
  if (wid >= n) return;
  half4_t h = ((const half4_t*)H)[(size_t)wid * 64 + lane];
  floatx4 w = ((const floatx4*)W3)[lane];
  float s = (float)h[0] * w[0] + (float)h[1] * w[1] + (float)h[2] * w[2] + (float)h[3] * w[3];
  for (int off = 32; off > 0; off >>= 1) s += __shfl_down(s, off);
  if (lane == 0) t3[wid] = s;
}

__global__ void final_kernel(const float* __restrict__ t3, const int* __restrict__ rowptr,
                             const int* __restrict__ csr, const float* __restrict__ csr_w,
                             const float* __restrict__ dinv, const float* __restrict__ b3,
                             float* __restrict__ out, int n) {
  int d = blockIdx.x * blockDim.x + threadIdx.x;
  if (d >= n) return;
  float acc = 0.f;
  int beg = rowptr[d], end = rowptr[d + 1];
  for (int j = beg; j < end; ++j) acc += csr_w[j] * t3[csr[j]];
  float di = dinv[d];
  out[d] = acc * di + t3[d] * di * di + b3[0];
}

// ---------------- launcher ----------------

extern "C" void kernel_launch(void* const* d_in, const int* in_sizes, int n_in,
                              void* d_out, int out_size, void* d_ws, size_t ws_size,
                              hipStream_t stream) {
  const float* x   = (const float*)d_in[0];
  const int* src   = (const int*)d_in[1];
  const int* dst   = (const int*)d_in[2];
  const int* batch = (const int*)d_in[3];
  const float* W0 = (const float*)d_in[4];
  const float* b0 = (const float*)d_in[5];
  const float* Wf = (const float*)d_in[6];
  const float* bf = (const float*)d_in[7];
  const float* W1 = (const float*)d_in[8];
  const float* b1 = (const float*)d_in[9];
  const float* W2 = (const float*)d_in[10];
  const float* b2 = (const float*)d_in[11];
  const float* W3 = (const float*)d_in[12];
  const float* b3 = (const float*)d_in[13];
  float* out = (float*)d_out;

  char* p = (char*)d_ws;
  auto alloc = [&](size_t bytes) { char* q = p; p += (bytes + 255) & ~(size_t)255; return q; };
  _Float16* hA   = (_Float16*)alloc((size_t)N_NODES * HID * 2);
  _Float16* hB   = (_Float16*)alloc((size_t)N_NODES * HID * 2);
  _Float16* xh   = (_Float16*)alloc((size_t)N_NODES * FEAT * 2);
  _Float16* W0t  = (_Float16*)alloc((size_t)HID * FEAT * 2);
  _Float16* W1t  = (_Float16*)alloc((size_t)HID * HID * 2);
  _Float16* W2at = (_Float16*)alloc((size_t)HID * HID * 2);
  int*   cnt    = (int*)alloc((size_t)N_NODES * 4);
  int*   rowptr = (int*)alloc((size_t)(N_NODES + 1) * 4);
  int*   cursor = (int*)alloc((size_t)N_NODES * 4);
  int*   csr    = (int*)alloc((size_t)N_EDGES * 4);
  float* csrw   = (float*)alloc((size_t)N_EDGES * 4);
  float* dinv   = (float*)alloc((size_t)N_NODES * 4);
  int*   bsum   = (int*)alloc(NB_SCAN * 4);
  int*   boff   = (int*)alloc(NB_SCAN * 4);
  int*   bounds = (int*)alloc(256 * 4);
  float* Ppart  = (float*)alloc((size_t)N_GRAPHS * POOL_SPLIT * HID * 4);
  float* gi2    = (float*)alloc((size_t)N_GRAPHS * HID * 4);
  float* t3     = (float*)alloc((size_t)N_NODES * 4);

  hipMemsetAsync(cnt, 0, (size_t)N_NODES * 4, stream);
  hipMemsetAsync(cursor, 0, (size_t)N_NODES * 4, stream);

  int eb = (N_EDGES + 255) / 256;
  int nb = NB_SCAN;

  // conversions (independent of graph preproc)
  xcvt_kernel<<<(N_NODES * FEAT / 4 + 255) / 256, 256, 0, stream>>>(x, xh, N_NODES * FEAT / 4);
  wcvt_kernel<<<(FEAT * 256 + 255) / 256, 256, 0, stream>>>(W0, W0t, FEAT);
  wcvt_kernel<<<(HID * 256 + 255) / 256, 256, 0, stream>>>(W1, W1t, HID);
  wcvt_kernel<<<(HID * 256 + 255) / 256, 256, 0, stream>>>(W2, W2at, HID);

  hist_kernel<<<eb, 256, 0, stream>>>(dst, cnt, N_EDGES);
  scan1_kernel<<<nb, 256, 0, stream>>>(cnt, dinv, bsum, N_NODES);
  scan2_kernel<<<1, 256, 0, stream>>>(bsum, boff, rowptr);
  scan3_kernel<<<nb, 256, 0, stream>>>(cnt, boff, rowptr, N_NODES);
  place_kernel<<<eb, 256, 0, stream>>>(dst, rowptr, cursor, csr, N_EDGES);
  sortrow_kernel<<<(N_NODES * 64 + 255) / 256, 256, 0, stream>>>(csr, csrw, rowptr, src, dinv, N_NODES);
  bounds_kernel<<<1, 128, 0, stream>>>(batch, bounds, N_NODES, N_GRAPHS);

  int gb = (N_NODES + 127) / 128;

  // conv0: Z0 = agg(xh) [N,128] -> hA ; h0 = relu(Z0@W0+b0) -> hB
  agg16_kernel<FEAT, false, false><<<(N_NODES + 15) / 16, 256, 0, stream>>>(xh, rowptr, csr, csrw, dinv, nullptr, hA, N_NODES);
  mfma_gemm<FEAT, true, true, false><<<gb, 256, 0, stream>>>(hA, W0t, b0, nullptr, nullptr, hB, N_NODES);

  // gi2 = (max-pool(h0) @ Wf + bf) @ W2[256:512]
  pool1_kernel<<<N_GRAPHS * POOL_SPLIT, 256, 0, stream>>>(hB, bounds, Ppart);
  pool2_kernel<<<N_GRAPHS, 256, 0, stream>>>(Ppart, Wf, bf, W2, gi2);

  // conv1 #1
  agg16_kernel<HID, false, false><<<(N_NODES + 7) / 8, 256, 0, stream>>>(hB, rowptr, csr, csrw, dinv, nullptr, hA, N_NODES);
  mfma_gemm<HID, true, true, false><<<gb, 256, 0, stream>>>(hA, W1t, b1, nullptr, nullptr, hB, N_NODES);

  // conv1 #2
  agg16_kernel<HID, false, false><<<(N_NODES + 7) / 8, 256, 0, stream>>>(hB, rowptr, csr, csrw, dinv, nullptr, hA, N_NODES);
  mfma_gemm<HID, true, true, false><<<gb, 256, 0, stream>>>(hA, W1t, b1, nullptr, nullptr, hB, N_NODES);

  // conv2: T2 = loc2@W2a + gi2[batch] -> hA ; h2 = relu(agg(T2)+b2) -> hB
  mfma_gemm<HID, false, false, true><<<gb, 256, 0, stream>>>(hB, W2at, nullptr, gi2, batch, hA, N_NODES);
  agg16_kernel<HID, true, true><<<(N_NODES + 7) / 8, 256, 0, stream>>>(hA, rowptr, csr, csrw, dinv, b2, hB, N_NODES);

  // conv3: t3 = h2@W3 ; logits = agg_scalar(t3) + b3
  dot16_kernel<<<(N_NODES * 64 + 255) / 256, 256, 0, stream>>>(hB, W3, t3, N_NODES);
  final_kernel<<<(N_NODES + 255) / 256, 256, 0, stream>>>(t3, rowptr, csr, csrw, dinv, b3, out, N_NODES);
}

// Round 5
// 482.459 us; speedup vs baseline: 3.0049x; 1.1544x over previous
//
#include <hip/hip_runtime.h>

#define N_NODES 50000
#define N_EDGES 800000
#define FEAT 128
#define HID 256
#define N_GRAPHS 64
#define NB_SCAN ((N_NODES + 255) / 256)
#define POOL_SPLIT 8

typedef float floatx4 __attribute__((ext_vector_type(4)));
typedef _Float16 half4_t __attribute__((ext_vector_type(4)));
typedef _Float16 half8_t __attribute__((ext_vector_type(8)));

// ---------------- graph preprocessing ----------------

__global__ void hist_kernel(const int* __restrict__ dst, int* __restrict__ cnt, int e) {
  int i = blockIdx.x * blockDim.x + threadIdx.x;
  if (i < e) atomicAdd(&cnt[dst[i]], 1);
}

__global__ __launch_bounds__(256) void scan1_kernel(const int* __restrict__ cnt,
                                                    float* __restrict__ dinv,
                                                    int* __restrict__ bsum, int n) {
  __shared__ int sh[256];
  int i = blockIdx.x * 256 + threadIdx.x;
  int c = (i < n) ? cnt[i] : 0;
  if (i < n) dinv[i] = 1.0f / sqrtf((float)c + 1.0f);
  sh[threadIdx.x] = c;
  __syncthreads();
  for (int off = 128; off > 0; off >>= 1) {
    if (threadIdx.x < off) sh[threadIdx.x] += sh[threadIdx.x + off];
    __syncthreads();
  }
  if (threadIdx.x == 0) bsum[blockIdx.x] = sh[0];
}

__global__ __launch_bounds__(256) void scan2_kernel(const int* __restrict__ bsum,
                                                    int* __restrict__ boff,
                                                    int* __restrict__ rowptr) {
  __shared__ int sh[256];
  int t = threadIdx.x;
  int v = (t < NB_SCAN) ? bsum[t] : 0;
  sh[t] = v;
  __syncthreads();
  for (int off = 1; off < 256; off <<= 1) {
    int u = (t >= off) ? sh[t - off] : 0;
    __syncthreads();
    sh[t] += u;
    __syncthreads();
  }
  if (t < NB_SCAN) boff[t] = (t == 0) ? 0 : sh[t - 1];
  if (t == 255) rowptr[N_NODES] = sh[255];
}

__global__ __launch_bounds__(256) void scan3_kernel(const int* __restrict__ cnt,
                                                    const int* __restrict__ boff,
                                                    int* __restrict__ rowptr, int n) {
  __shared__ int sh[256];
  int i = blockIdx.x * 256 + threadIdx.x;
  int c = (i < n) ? cnt[i] : 0;
  sh[threadIdx.x] = c;
  __syncthreads();
  for (int off = 1; off < 256; off <<= 1) {
    int u = (threadIdx.x >= off) ? sh[threadIdx.x - off] : 0;
    __syncthreads();
    sh[threadIdx.x] += u;
    __syncthreads();
  }
  if (i < n) rowptr[i] = boff[blockIdx.x] + sh[threadIdx.x] - c;
}

__global__ void place_kernel(const int* __restrict__ dst, const int* __restrict__ rowptr,
                             int* __restrict__ cursor, int* __restrict__ csr, int e) {
  int i = blockIdx.x * blockDim.x + threadIdx.x;
  if (i < e) {
    int d = dst[i];
    int slot = rowptr[d] + atomicAdd(&cursor[d], 1);
    csr[slot] = i;
  }
}

// one wave per row: bitonic sort of edge ids, rewrite as (src, dinv[src])
__global__ __launch_bounds__(256) void sortrow_kernel(
    int* __restrict__ csr, float* __restrict__ csr_w, const int* __restrict__ rowptr,
    const int* __restrict__ src, const float* __restrict__ dinv, int n) {
  int wid = (blockIdx.x * 256 + threadIdx.x) >> 6;
  int lane = threadIdx.x & 63;
  if (wid >= n) return;
  int beg = rowptr[wid], len = rowptr[wid + 1] - beg;
  if (len <= 64) {
    int v = (lane < len) ? csr[beg + lane] : 0x7fffffff;
    #pragma unroll
    for (int k = 2; k <= 64; k <<= 1) {
      #pragma unroll
      for (int j = k >> 1; j >= 1; j >>= 1) {
        int other = __shfl_xor(v, j);
        int mn = min(v, other), mx = max(v, other);
        bool up = (lane & k) == 0;
        v = (((lane & j) == 0) == up) ? mn : mx;
      }
    }
    if (lane < len) {
      int s = src[v];
      csr[beg + lane] = s;
      csr_w[beg + lane] = dinv[s];
    }
  } else if (lane == 0) {
    for (int a = 0; a < len; ++a)
      for (int b = a + 1; b < len; ++b) {
        int xa = csr[beg + a], xb = csr[beg + b];
        if (xb < xa) { csr[beg + a] = xb; csr[beg + b] = xa; }
      }
    for (int a = 0; a < len; ++a) {
      int s = src[csr[beg + a]];
      csr[beg + a] = s;
      csr_w[beg + a] = dinv[s];
    }
  }
}

__global__ void bounds_kernel(const int* __restrict__ batch, int* __restrict__ bounds,
                              int n, int g) {
  int t = threadIdx.x;
  if (t > g) return;
  int lo = 0, hi = n;
  while (lo < hi) { int mid = (lo + hi) >> 1; if (batch[mid] < t) lo = mid + 1; else hi = mid; }
  bounds[t] = lo;
}

// ---------------- conversions ----------------

__global__ void xcvt_kernel(const float* __restrict__ x, _Float16* __restrict__ xh, int n4) {
  int i = blockIdx.x * blockDim.x + threadIdx.x;
  if (i >= n4) return;
  floatx4 v = ((const floatx4*)x)[i];
  half4_t h;
  h[0] = (_Float16)v[0]; h[1] = (_Float16)v[1];
  h[2] = (_Float16)v[2]; h[3] = (_Float16)v[3];
  ((half4_t*)xh)[i] = h;
}

// all three weight transposes in one launch: Bt[c][k] = (f16) W[k][c]
__global__ void wcvt3_kernel(const float* __restrict__ W0, _Float16* __restrict__ W0t,
                             const float* __restrict__ W1, _Float16* __restrict__ W1t,
                             const float* __restrict__ W2, _Float16* __restrict__ W2at) {
  int idx = blockIdx.x * blockDim.x + threadIdx.x;
  if (idx < FEAT * 256) {
    int c = idx / FEAT, k = idx - c * FEAT;
    W0t[idx] = (_Float16)W0[k * 256 + c];
    return;
  }
  idx -= FEAT * 256;
  if (idx < HID * 256) {
    int c = idx / HID, k = idx - c * HID;
    W1t[idx] = (_Float16)W1[k * 256 + c];
    return;
  }
  idx -= HID * 256;
  if (idx < HID * 256) {
    int c = idx / HID, k = idx - c * HID;
    W2at[idx] = (_Float16)W2[k * 256 + c];
  }
}

// ---------------- aggregation (f16 in/out, f32 accumulate) ----------------
template <int F, bool BIAS, bool RELU>
__global__ __launch_bounds__(256) void agg16_kernel(
    const _Float16* __restrict__ T, const int* __restrict__ rowptr,
    const int* __restrict__ csr, const float* __restrict__ csr_w,
    const float* __restrict__ dinv, const float* __restrict__ bias,
    _Float16* __restrict__ out, int n) {
  constexpr int LPR = F / 8;
  constexpr int RPB = 256 / LPR;
  int li = threadIdx.x & (LPR - 1);
  int d = blockIdx.x * RPB + threadIdx.x / LPR;
  if (d >= n) return;
  const half8_t* Tv = (const half8_t*)T;
  int beg = rowptr[d], end = rowptr[d + 1];
  float acc[8];
  #pragma unroll
  for (int e = 0; e < 8; ++e) acc[e] = 0.f;
  int j = beg;
  for (; j + 4 <= end; j += 4) {
    int s0 = csr[j], s1 = csr[j + 1], s2 = csr[j + 2], s3 = csr[j + 3];
    float w0 = csr_w[j], w1 = csr_w[j + 1], w2 = csr_w[j + 2], w3 = csr_w[j + 3];
    half8_t v0 = Tv[(size_t)s0 * LPR + li];
    half8_t v1 = Tv[(size_t)s1 * LPR + li];
    half8_t v2 = Tv[(size_t)s2 * LPR + li];
    half8_t v3 = Tv[(size_t)s3 * LPR + li];
    #pragma unroll
    for (int e = 0; e < 8; ++e)
      acc[e] += w0 * (float)v0[e] + w1 * (float)v1[e] + w2 * (float)v2[e] + w3 * (float)v3[e];
  }
  for (; j < end; ++j) {
    int s0 = csr[j];
    float w0 = csr_w[j];
    half8_t v0 = Tv[(size_t)s0 * LPR + li];
    #pragma unroll
    for (int e = 0; e < 8; ++e) acc[e] += w0 * (float)v0[e];
  }
  float di = dinv[d];
  half8_t vs = Tv[(size_t)d * LPR + li];
  half8_t o;
  #pragma unroll
  for (int e = 0; e < 8; ++e) {
    float v = acc[e] * di + (float)vs[e] * di * di;
    if (BIAS) v += bias[li * 8 + e];
    if (RELU) v = fmaxf(v, 0.f);
    o[e] = (_Float16)v;
  }
  ((half8_t*)out)[(size_t)d * LPR + li] = o;
}

// ---- agg + bias + relu + dot(W3): t3[d] = relu(agg(T)[d] + b2) . W3  (h2 never stored)
__global__ __launch_bounds__(256) void agg_dot_kernel(
    const _Float16* __restrict__ T, const int* __restrict__ rowptr,
    const int* __restrict__ csr, const float* __restrict__ csr_w,
    const float* __restrict__ dinv, const float* __restrict__ bias,
    const float* __restrict__ W3, float* __restrict__ t3, int n) {
  constexpr int LPR = 32;
  int li = threadIdx.x & (LPR - 1);
  int d = blockIdx.x * 8 + threadIdx.x / LPR;
  if (d >= n) return;
  const half8_t* Tv = (const half8_t*)T;
  int beg = rowptr[d], end = rowptr[d + 1];
  float acc[8];
  #pragma unroll
  for (int e = 0; e < 8; ++e) acc[e] = 0.f;
  int j = beg;
  for (; j + 4 <= end; j += 4) {
    int s0 = csr[j], s1 = csr[j + 1], s2 = csr[j + 2], s3 = csr[j + 3];
    float w0 = csr_w[j], w1 = csr_w[j + 1], w2 = csr_w[j + 2], w3 = csr_w[j + 3];
    half8_t v0 = Tv[(size_t)s0 * LPR + li];
    half8_t v1 = Tv[(size_t)s1 * LPR + li];
    half8_t v2 = Tv[(size_t)s2 * LPR + li];
    half8_t v3 = Tv[(size_t)s3 * LPR + li];
    #pragma unroll
    for (int e = 0; e < 8; ++e)
      acc[e] += w0 * (float)v0[e] + w1 * (float)v1[e] + w2 * (float)v2[e] + w3 * (float)v3[e];
  }
  for (; j < end; ++j) {
    int s0 = csr[j];
    float w0 = csr_w[j];
    half8_t v0 = Tv[(size_t)s0 * LPR + li];
    #pragma unroll
    for (int e = 0; e < 8; ++e) acc[e] += w0 * (float)v0[e];
  }
  float di = dinv[d];
  half8_t vs = Tv[(size_t)d * LPR + li];
  floatx4 w3a = *(const floatx4*)(W3 + li * 8);
  floatx4 w3b = *(const floatx4*)(W3 + li * 8 + 4);
  float s = 0.f;
  #pragma unroll
  for (int e = 0; e < 8; ++e) {
    float v = acc[e] * di + (float)vs[e] * di * di + bias[li * 8 + e];
    v = fmaxf(v, 0.f);
    s += v * ((e < 4) ? w3a[e] : w3b[e - 4]);
  }
  #pragma unroll
  for (int off = 1; off < 32; off <<= 1) s += __shfl_xor(s, off);
  if (li == 0) t3[d] = s;
}

// ---------------- tiled MFMA GEMM ----------------
// C[128-row tile x 256] = A_tile @ Bt^T. A staged in LDS (XOR-swizzled);
// wave w owns cols [w*64, w*64+64) for all 128 rows -> Bt read ONCE per block.
template <int K, bool BIAS, bool RELU, bool GIADD>
__global__ __launch_bounds__(256) void gemm_tile(
    const _Float16* __restrict__ A, const _Float16* __restrict__ Bt,
    const float* __restrict__ bias, const float* __restrict__ gi2,
    const int* __restrict__ batch, _Float16* __restrict__ C, int nrows) {
  constexpr int ROWB = K * 2;        // bytes per LDS row
  constexpr int CPR = K / 8;         // 16B chunks per row
  __shared__ _Float16 smem[128 * K];
  char* sb = (char*)smem;
  int tid = threadIdx.x;
  int row0 = blockIdx.x * 128;

  // stage A tile: 128 rows x CPR chunks = 16*K chunks; 256 threads -> K/16 iters
  #pragma unroll
  for (int it = 0; it < K / 16; ++it) {
    int e = it * 256 + tid;
    int r = e / CPR;
    int cof = (e - r * CPR) * 16;    // byte offset in row
    int grow = min(row0 + r, nrows - 1);
    half8_t v = *(const half8_t*)(A + (size_t)grow * K + cof / 2);
    *(half8_t*)&sb[r * ROWB + (cof ^ ((r & 7) << 4))] = v;
  }
  __syncthreads();

  int lane = tid & 63, wv = tid >> 6;
  int rlo = lane & 15, khi = lane >> 4;
  int cw0 = wv * 64;
  floatx4 acc[8][4];
  #pragma unroll
  for (int h = 0; h < 8; ++h)
    #pragma unroll
    for (int g = 0; g < 4; ++g)
      { acc[h][g][0] = 0.f; acc[h][g][1] = 0.f; acc[h][g][2] = 0.f; acc[h][g][3] = 0.f; }

  for (int kc = 0; kc < K; kc += 32) {
    int kbyte = kc * 2 + khi * 16;
    half8_t xa[8];
    #pragma unroll
    for (int h = 0; h < 8; ++h) {
      int r = h * 16 + rlo;
      xa[h] = *(half8_t*)&sb[r * ROWB + (kbyte ^ ((r & 7) << 4))];
    }
    #pragma unroll
    for (int g = 0; g < 4; ++g) {
      half8_t wb = *(const half8_t*)(Bt + (size_t)(cw0 + g * 16 + rlo) * K + kc + khi * 8);
      #pragma unroll
      for (int h = 0; h < 8; ++h)
        acc[h][g] = __builtin_amdgcn_mfma_f32_16x16x32_f16(wb, xa[h], acc[h][g], 0, 0, 0);
    }
  }

  #pragma unroll
  for (int h = 0; h < 8; ++h) {
    int crow = row0 + h * 16 + rlo;
    if (crow >= nrows) continue;
    const float* gp = nullptr;
    if (GIADD) gp = gi2 + (size_t)batch[crow] * HID;
    #pragma unroll
    for (int g = 0; g < 4; ++g) {
      int c0 = cw0 + g * 16 + khi * 4;
      floatx4 v = acc[h][g];
      if (BIAS) v += *(const floatx4*)(bias + c0);
      if (GIADD) v += *(const floatx4*)(gp + c0);
      if (RELU) {
        v[0] = fmaxf(v[0], 0.f); v[1] = fmaxf(v[1], 0.f);
        v[2] = fmaxf(v[2], 0.f); v[3] = fmaxf(v[3], 0.f);
      }
      half4_t hv;
      hv[0] = (_Float16)v[0]; hv[1] = (_Float16)v[1];
      hv[2] = (_Float16)v[2]; hv[3] = (_Float16)v[3];
      *(half4_t*)(C + (size_t)crow * HID + c0) = hv;
    }
  }
}

// ---------------- pooling (split) -> fc1 -> @W2[256:512] ----------------

__global__ __launch_bounds__(256) void pool1_kernel(const _Float16* __restrict__ h0,
                                                    const int* __restrict__ bounds,
                                                    float* __restrict__ Ppart) {
  int g = blockIdx.x / POOL_SPLIT, s = blockIdx.x % POOL_SPLIT;
  int c = threadIdx.x;
  int beg = bounds[g], end = bounds[g + 1];
  float m = -INFINITY;
  for (int i = beg + s; i < end; i += POOL_SPLIT)
    m = fmaxf(m, (float)h0[(size_t)i * HID + c]);
  Ppart[(size_t)(g * POOL_SPLIT + s) * HID + c] = m;
}

__global__ __launch_bounds__(256) void pool2_kernel(const float* __restrict__ Ppart,
                                                    const float* __restrict__ Wf,
                                                    const float* __restrict__ bf,
                                                    const float* __restrict__ W2,
                                                    float* __restrict__ gi2) {
  __shared__ float P[HID];
  __shared__ float GI[HID];
  int g = blockIdx.x;
  int c = threadIdx.x;
  float m = -INFINITY;
  #pragma unroll
  for (int s = 0; s < POOL_SPLIT; ++s)
    m = fmaxf(m, Ppart[(size_t)(g * POOL_SPLIT + s) * HID + c]);
  P[c] = m;
  __syncthreads();
  float a = 0.f;
  for (int k = 0; k < HID; ++k) a += P[k] * Wf[k * HID + c];
  GI[c] = a + bf[c];
  __syncthreads();
  float a2 = 0.f;
  for (int k = 0; k < HID; ++k) a2 += GI[k] * W2[(HID + k) * HID + c];
  gi2[g * HID + c] = a2;
}

__global__ void final_kernel(const float* __restrict__ t3, const int* __restrict__ rowptr,
                             const int* __restrict__ csr, const float* __restrict__ csr_w,
                             const float* __restrict__ dinv, const float* __restrict__ b3,
                             float* __restrict__ out, int n) {
  int d = blockIdx.x * blockDim.x + threadIdx.x;
  if (d >= n) return;
  float acc = 0.f;
  int beg = rowptr[d], end = rowptr[d + 1];
  for (int j = beg; j < end; ++j) acc += csr_w[j] * t3[csr[j]];
  float di = dinv[d];
  out[d] = acc * di + t3[d] * di * di + b3[0];
}

// ---------------- launcher ----------------

extern "C" void kernel_launch(void* const* d_in, const int* in_sizes, int n_in,
                              void* d_out, int out_size, void* d_ws, size_t ws_size,
                              hipStream_t stream) {
  const float* x   = (const float*)d_in[0];
  const int* src   = (const int*)d_in[1];
  const int* dst   = (const int*)d_in[2];
  const int* batch = (const int*)d_in[3];
  const float* W0 = (const float*)d_in[4];
  const float* b0 = (const float*)d_in[5];
  const float* Wf = (const float*)d_in[6];
  const float* bf = (const float*)d_in[7];
  const float* W1 = (const float*)d_in[8];
  const float* b1 = (const float*)d_in[9];
  const float* W2 = (const float*)d_in[10];
  const float* b2 = (const float*)d_in[11];
  const float* W3 = (const float*)d_in[12];
  const float* b3 = (const float*)d_in[13];
  float* out = (float*)d_out;

  char* p = (char*)d_ws;
  auto alloc = [&](size_t bytes) { char* q = p; p += (bytes + 255) & ~(size_t)255; return q; };
  _Float16* hA   = (_Float16*)alloc((size_t)N_NODES * HID * 2);
  _Float16* hB   = (_Float16*)alloc((size_t)N_NODES * HID * 2);
  _Float16* xh   = (_Float16*)alloc((size_t)N_NODES * FEAT * 2);
  _Float16* W0t  = (_Float16*)alloc((size_t)HID * FEAT * 2);
  _Float16* W1t  = (_Float16*)alloc((size_t)HID * HID * 2);
  _Float16* W2at = (_Float16*)alloc((size_t)HID * HID * 2);
  int*   cnt    = (int*)alloc((size_t)N_NODES * 4);
  int*   rowptr = (int*)alloc((size_t)(N_NODES + 1) * 4);
  int*   cursor = (int*)alloc((size_t)N_NODES * 4);
  int*   csr    = (int*)alloc((size_t)N_EDGES * 4);
  float* csrw   = (float*)alloc((size_t)N_EDGES * 4);
  float* dinv   = (float*)alloc((size_t)N_NODES * 4);
  int*   bsum   = (int*)alloc(NB_SCAN * 4);
  int*   boff   = (int*)alloc(NB_SCAN * 4);
  int*   bounds = (int*)alloc(256 * 4);
  float* Ppart  = (float*)alloc((size_t)N_GRAPHS * POOL_SPLIT * HID * 4);
  float* gi2    = (float*)alloc((size_t)N_GRAPHS * HID * 4);
  float* t3     = (float*)alloc((size_t)N_NODES * 4);

  hipMemsetAsync(cnt, 0, (size_t)N_NODES * 4, stream);
  hipMemsetAsync(cursor, 0, (size_t)N_NODES * 4, stream);

  int eb = (N_EDGES + 255) / 256;
  int nb = NB_SCAN;

  xcvt_kernel<<<(N_NODES * FEAT / 4 + 255) / 256, 256, 0, stream>>>(x, xh, N_NODES * FEAT / 4);
  wcvt3_kernel<<<((FEAT + 2 * HID) * 256 + 255) / 256, 256, 0, stream>>>(W0, W0t, W1, W1t, W2, W2at);

  hist_kernel<<<eb, 256, 0, stream>>>(dst, cnt, N_EDGES);
  scan1_kernel<<<nb, 256, 0, stream>>>(cnt, dinv, bsum, N_NODES);
  scan2_kernel<<<1, 256, 0, stream>>>(bsum, boff, rowptr);
  scan3_kernel<<<nb, 256, 0, stream>>>(cnt, boff, rowptr, N_NODES);
  place_kernel<<<eb, 256, 0, stream>>>(dst, rowptr, cursor, csr, N_EDGES);
  sortrow_kernel<<<(N_NODES * 64 + 255) / 256, 256, 0, stream>>>(csr, csrw, rowptr, src, dinv, N_NODES);
  bounds_kernel<<<1, 128, 0, stream>>>(batch, bounds, N_NODES, N_GRAPHS);

  int gb = (N_NODES + 127) / 128;

  // conv0
  agg16_kernel<FEAT, false, false><<<(N_NODES + 15) / 16, 256, 0, stream>>>(xh, rowptr, csr, csrw, dinv, nullptr, hA, N_NODES);
  gemm_tile<FEAT, true, true, false><<<gb, 256, 0, stream>>>(hA, W0t, b0, nullptr, nullptr, hB, N_NODES);

  // gi2
  pool1_kernel<<<N_GRAPHS * POOL_SPLIT, 256, 0, stream>>>(hB, bounds, Ppart);
  pool2_kernel<<<N_GRAPHS, 256, 0, stream>>>(Ppart, Wf, bf, W2, gi2);

  // conv1 #1
  agg16_kernel<HID, false, false><<<(N_NODES + 7) / 8, 256, 0, stream>>>(hB, rowptr, csr, csrw, dinv, nullptr, hA, N_NODES);
  gemm_tile<HID, true, true, false><<<gb, 256, 0, stream>>>(hA, W1t, b1, nullptr, nullptr, hB, N_NODES);

  // conv1 #2
  agg16_kernel<HID, false, false><<<(N_NODES + 7) / 8, 256, 0, stream>>>(hB, rowptr, csr, csrw, dinv, nullptr, hA, N_NODES);
  gemm_tile<HID, true, true, false><<<gb, 256, 0, stream>>>(hA, W1t, b1, nullptr, nullptr, hB, N_NODES);

  // conv2: T2 = loc2@W2a + gi2[batch] -> hA ; then agg+bias+relu+dot(W3) -> t3
  gemm_tile<HID, false, false, true><<<gb, 256, 0, stream>>>(hB, W2at, nullptr, gi2, batch, hA, N_NODES);
  agg_dot_kernel<<<(N_NODES + 7) / 8, 256, 0, stream>>>(hA, rowptr, csr, csrw, dinv, b2, W3, t3, N_NODES);

  // conv3 aggregation (scalar)
  final_kernel<<<(N_NODES + 255) / 256, 256, 0, stream>>>(t3, rowptr, csr, csrw, dinv, b3, out, N_NODES);
}